// Round 4
// baseline (328.319 us; speedup 1.0000x reference)
//
#include <hip/hip_runtime.h>

// log2(1e-7): frac < 1e-7  <=>  log2(frac) < this
#define LOG2_EPS_CLAMP -23.2534966f

__device__ __forceinline__ float flog2(float x) { return __builtin_amdgcn_logf(x); }

// 8 sub-threads per neuron: sub s = (tid>>3)&7 owns i in {2s, 2s+1}.
// g = (tid&7) + (tid>>6)*8 -> adjacent lanes cover adjacent neurons; 32 neurons/block.
__global__ __launch_bounds__(256, 5) void pid_kernel(const float* __restrict__ p,
                                                     float* __restrict__ out,
                                                     const int N) {
    const int tid = threadIdx.x;
    const int s = (tid >> 3) & 7;
    const int g = (tid & 7) + ((tid >> 6) << 3);
    const int n = blockIdx.x * 32 + g;
    if (n >= N) return;
    const float* __restrict__ q = p + n;

    // partial m12 (over own 2 i's) + own-i m02 slices, all registers
    float m12p[32];
    #pragma unroll
    for (int t = 0; t < 32; ++t) m12p[t] = 0.f;
    float a0[2], a1[2];

    // ---- phase 1: partial marginals ----
    #pragma unroll
    for (int ii = 0; ii < 2; ++ii) {
        const int i = s * 2 + ii;
        const float* __restrict__ qi = q + (size_t)(i * 32) * (size_t)N;
        float s0 = 0.f, s1 = 0.f;
        #pragma unroll
        for (int j = 0; j < 16; ++j) {
            const float f0 = qi[(size_t)(2 * j) * (size_t)N];
            const float f1 = qi[(size_t)(2 * j + 1) * (size_t)N];
            s0 += f0; s1 += f1;
            m12p[2 * j]     += f0;
            m12p[2 * j + 1] += f1;
        }
        a0[ii] = s0; a1[ii] = s1;
    }

    // butterfly-reduce m12 across the 8 sub-threads (lane xor 8,16,32)
    #pragma unroll
    for (int t = 0; t < 32; ++t) {
        m12p[t] += __shfl_xor(m12p[t], 8, 64);
        m12p[t] += __shfl_xor(m12p[t], 16, 64);
        m12p[t] += __shfl_xor(m12p[t], 32, 64);
    }

    float P20 = 0.f, P21 = 0.f;
    #pragma unroll
    for (int j = 0; j < 16; ++j) { P20 += m12p[2 * j]; P21 += m12p[2 * j + 1]; }
    const float LP20 = flog2(P20);
    const float LP21 = flog2(P21);

    // ---- phase 2: I1 ({0}{1}), I4 ({01}), I2 folded per own i ----
    float I1 = 0.f, I2 = 0.f, I4 = 0.f;
    #pragma unroll
    for (int ii = 0; ii < 2; ++ii) {
        const int i = s * 2 + ii;
        const float a0i = a0[ii], a1i = a1[ii];
        const float m0i = a0i + a1i;
        const float* __restrict__ qi = q + (size_t)(i * 32) * (size_t)N;
        #pragma unroll
        for (int j = 0; j < 16; ++j) {
            const float f0  = qi[(size_t)(2 * j) * (size_t)N];
            const float f1  = qi[(size_t)(2 * j + 1) * (size_t)N];
            const float p01 = f0 + f1;
            const float m1j = m12p[2 * j] + m12p[2 * j + 1];
            const float u1  = m0i + m1j - p01;
            const float Lu1  = flog2(u1);
            const float Lp01 = flog2(p01);
            // k = 0
            {
                const float num = a0i + m12p[2 * j] - f0;
                float l1 = flog2(num) - Lu1 - LP20;
                l1 = (l1 < LOG2_EPS_CLAMP) ? 0.f : l1;
                I1 = fmaf(f0, l1, I1);
                float l4 = flog2(f0) - Lp01 - LP20;
                l4 = (l4 < LOG2_EPS_CLAMP) ? 0.f : l4;
                I4 = fmaf(f0, l4, I4);
            }
            // k = 1
            {
                const float num = a1i + m12p[2 * j + 1] - f1;
                float l1 = flog2(num) - Lu1 - LP21;
                l1 = (l1 < LOG2_EPS_CLAMP) ? 0.f : l1;
                I1 = fmaf(f1, l1, I1);
                float l4 = flog2(f1) - Lp01 - LP21;
                l4 = (l4 < LOG2_EPS_CLAMP) ? 0.f : l4;
                I4 = fmaf(f1, l4, I4);
            }
        }
        // I2 contribution of this i
        const float L0 = flog2(m0i);
        float la = flog2(a0i) - L0 - LP20;
        la = (la < LOG2_EPS_CLAMP) ? 0.f : la;
        I2 = fmaf(a0i, la, I2);
        float lb = flog2(a1i) - L0 - LP21;
        lb = (lb < LOG2_EPS_CLAMP) ? 0.f : lb;
        I2 = fmaf(a1i, lb, I2);
    }

    // reduce I1, I2, I4 across the 8 sub-threads
    I1 += __shfl_xor(I1, 8, 64); I1 += __shfl_xor(I1, 16, 64); I1 += __shfl_xor(I1, 32, 64);
    I2 += __shfl_xor(I2, 8, 64); I2 += __shfl_xor(I2, 16, 64); I2 += __shfl_xor(I2, 32, 64);
    I4 += __shfl_xor(I4, 8, 64); I4 += __shfl_xor(I4, 16, 64); I4 += __shfl_xor(I4, 32, 64);

    // ---- I3 = I(X1;Y): uniform within the group (full m12) ----
    float I3 = 0.f;
    #pragma unroll
    for (int j = 0; j < 16; ++j) {
        const float L1 = flog2(m12p[2 * j] + m12p[2 * j + 1]);
        float la = flog2(m12p[2 * j]) - L1 - LP20;
        la = (la < LOG2_EPS_CLAMP) ? 0.f : la;
        I3 = fmaf(m12p[2 * j], la, I3);
        float lb = flog2(m12p[2 * j + 1]) - L1 - LP21;
        lb = (lb < LOG2_EPS_CLAMP) ? 0.f : lb;
        I3 = fmaf(m12p[2 * j + 1], lb, I3);
    }

    const float H = -(P20 * flog2(P20 + 1e-10f) + P21 * flog2(P21 + 1e-10f));

    if (s == 0) {
        out[0 * N + n] = I1;
        out[1 * N + n] = I2 - I1;
        out[2 * N + n] = I3 - I1;
        out[3 * N + n] = I1 - I2 - I3 + I4;
        out[4 * N + n] = H - I4;
    }
}

extern "C" void kernel_launch(void* const* d_in, const int* in_sizes, int n_in,
                              void* d_out, int out_size, void* d_ws, size_t ws_size,
                              hipStream_t stream) {
    const float* p = (const float*)d_in[0];
    float* out = (float*)d_out;
    const int N = in_sizes[0] / 512;          // (16*16*2) bins per neuron
    const int blocks = (N + 31) / 32;         // 8 threads per neuron, 256/block
    pid_kernel<<<blocks, 256, 0, stream>>>(p, out, N);
}

// Round 5
// 308.004 us; speedup vs baseline: 1.0660x; 1.0660x over previous
//
#include <hip/hip_runtime.h>

// log2(1e-7): frac < 1e-7  <=>  log2(frac) < this
#define LOG2_EPS_CLAMP -23.2534966f

__device__ __forceinline__ float flog2(float x) { return __builtin_amdgcn_logf(x); }

// 16 sub-threads per neuron: sub s = (tid>>2)&15 owns i = s.
// g = (tid&3) + (tid>>6)*4 -> 4 consecutive neurons per 4-lane cluster;
// 16 neurons per 256-thread block; butterfly over lane-xor {4,8,16,32}.
__global__ __launch_bounds__(256) void pid_kernel(const float* __restrict__ p,
                                                  float* __restrict__ out,
                                                  const int N) {
    const int tid = threadIdx.x;
    const int s = (tid >> 2) & 15;          // owned i
    const int g = (tid & 3) + ((tid >> 6) << 2);
    const int n = blockIdx.x * 16 + g;
    if (n >= N) return;
    const float* __restrict__ q = p + n;
    const float* __restrict__ qi = q + (size_t)(s * 32) * (size_t)N;

    // partial m12 (own i only) + own-i m02 slices, all registers
    float m12p[32];
    float a0 = 0.f, a1 = 0.f;

    // ---- phase 1: partial marginals ----
    #pragma unroll
    for (int j = 0; j < 16; ++j) {
        const float f0 = qi[(size_t)(2 * j) * (size_t)N];
        const float f1 = qi[(size_t)(2 * j + 1) * (size_t)N];
        a0 += f0; a1 += f1;
        m12p[2 * j]     = f0;
        m12p[2 * j + 1] = f1;
    }

    // butterfly-reduce m12 across the 16 sub-threads (lane xor 4,8,16,32)
    #pragma unroll
    for (int t = 0; t < 32; ++t) {
        m12p[t] += __shfl_xor(m12p[t], 4, 64);
        m12p[t] += __shfl_xor(m12p[t], 8, 64);
        m12p[t] += __shfl_xor(m12p[t], 16, 64);
        m12p[t] += __shfl_xor(m12p[t], 32, 64);
    }

    float P20 = 0.f, P21 = 0.f;
    #pragma unroll
    for (int j = 0; j < 16; ++j) { P20 += m12p[2 * j]; P21 += m12p[2 * j + 1]; }
    const float LP20 = flog2(P20);
    const float LP21 = flog2(P21);

    // ---- phase 2: I1 ({0}{1}), I4 ({01}), I2 for own i ----
    float I1 = 0.f, I4 = 0.f;
    const float m0i = a0 + a1;
    #pragma unroll
    for (int j = 0; j < 16; ++j) {
        const float f0  = qi[(size_t)(2 * j) * (size_t)N];
        const float f1  = qi[(size_t)(2 * j + 1) * (size_t)N];
        const float p01 = f0 + f1;
        const float m1j = m12p[2 * j] + m12p[2 * j + 1];
        const float u1  = m0i + m1j - p01;
        const float Lu1  = flog2(u1);
        const float Lp01 = flog2(p01);
        // k = 0
        {
            const float num = a0 + m12p[2 * j] - f0;
            float l1 = flog2(num) - Lu1 - LP20;
            l1 = (l1 < LOG2_EPS_CLAMP) ? 0.f : l1;
            I1 = fmaf(f0, l1, I1);
            float l4 = flog2(f0) - Lp01 - LP20;
            l4 = (l4 < LOG2_EPS_CLAMP) ? 0.f : l4;
            I4 = fmaf(f0, l4, I4);
        }
        // k = 1
        {
            const float num = a1 + m12p[2 * j + 1] - f1;
            float l1 = flog2(num) - Lu1 - LP21;
            l1 = (l1 < LOG2_EPS_CLAMP) ? 0.f : l1;
            I1 = fmaf(f1, l1, I1);
            float l4 = flog2(f1) - Lp01 - LP21;
            l4 = (l4 < LOG2_EPS_CLAMP) ? 0.f : l4;
            I4 = fmaf(f1, l4, I4);
        }
    }

    // I2 contribution of own i
    float I2;
    {
        const float L0 = flog2(m0i);
        float la = flog2(a0) - L0 - LP20;
        la = (la < LOG2_EPS_CLAMP) ? 0.f : la;
        float lb = flog2(a1) - L0 - LP21;
        lb = (lb < LOG2_EPS_CLAMP) ? 0.f : lb;
        I2 = a0 * la + a1 * lb;
    }

    // reduce I1, I2, I4 across the 16 sub-threads
    #pragma unroll
    for (int m = 4; m <= 32; m <<= 1) {
        I1 += __shfl_xor(I1, m, 64);
        I2 += __shfl_xor(I2, m, 64);
        I4 += __shfl_xor(I4, m, 64);
    }

    // ---- I3 = I(X1;Y): uniform within the group (full m12) ----
    float I3 = 0.f;
    #pragma unroll
    for (int j = 0; j < 16; ++j) {
        const float L1 = flog2(m12p[2 * j] + m12p[2 * j + 1]);
        float la = flog2(m12p[2 * j]) - L1 - LP20;
        la = (la < LOG2_EPS_CLAMP) ? 0.f : la;
        I3 = fmaf(m12p[2 * j], la, I3);
        float lb = flog2(m12p[2 * j + 1]) - L1 - LP21;
        lb = (lb < LOG2_EPS_CLAMP) ? 0.f : lb;
        I3 = fmaf(m12p[2 * j + 1], lb, I3);
    }

    const float H = -(P20 * flog2(P20 + 1e-10f) + P21 * flog2(P21 + 1e-10f));

    if (s == 0) {
        out[0 * N + n] = I1;
        out[1 * N + n] = I2 - I1;
        out[2 * N + n] = I3 - I1;
        out[3 * N + n] = I1 - I2 - I3 + I4;
        out[4 * N + n] = H - I4;
    }
}

extern "C" void kernel_launch(void* const* d_in, const int* in_sizes, int n_in,
                              void* d_out, int out_size, void* d_ws, size_t ws_size,
                              hipStream_t stream) {
    const float* p = (const float*)d_in[0];
    float* out = (float*)d_out;
    const int N = in_sizes[0] / 512;          // (16*16*2) bins per neuron
    const int blocks = (N + 15) / 16;         // 16 threads per neuron, 256/block
    pid_kernel<<<blocks, 256, 0, stream>>>(p, out, N);
}